// Round 1
// baseline (1702.168 us; speedup 1.0000x reference)
//
#include <hip/hip_runtime.h>
#include <hip/hip_bf16.h>
#include <stdint.h>

#define S_ 2048
#define D_ 1024
#define B_ 8
#define KEXP 3072            // 3 * D : [h,l,h] x [h,h,l] fp16 expansion
#define NEGC 1e9f

typedef _Float16 f16;
typedef _Float16 f16x8 __attribute__((ext_vector_type(8)));
typedef float f32x4 __attribute__((ext_vector_type(4)));

// ---------------------------------------------------------------------------
// K0a/K0b: split fp32 -> fp16 hi/lo 3-term expansion, input pre-scaled by 64.
// pattern A (q): out[3t]=h, out[3t+1]=l, out[3t+2]=h
// pattern B (k): out[3t]=h, out[3t+1]=h, out[3t+2]=l
// so sum over expanded K gives h*h + l*h + h*l ~= (64q)*(64k); epilogue *2^-12.
// ---------------------------------------------------------------------------
__global__ __launch_bounds__(256) void split_expand(const float* __restrict__ in,
                                                    f16* __restrict__ out, int isB) {
  size_t idx = (size_t)blockIdx.x * 256 + threadIdx.x;   // one thread per 8 floats
  const float4* ip = (const float4*)(in + idx * 8);
  float4 a = ip[0], b = ip[1];
  float vv[8] = {a.x, a.y, a.z, a.w, b.x, b.y, b.z, b.w};
  union { f16 h[24]; uint4 u[3]; } o;
#pragma unroll
  for (int t = 0; t < 8; ++t) {
    float v = vv[t] * 64.0f;
    f16 h = (f16)v;
    float r = v - (float)h;      // exact (Sterbenz)
    f16 l = (f16)r;
    o.h[3 * t + 0] = h;
    o.h[3 * t + 1] = isB ? h : l;
    o.h[3 * t + 2] = isB ? l : h;
  }
  uint4* op = (uint4*)(out + idx * 24);
  op[0] = o.u[0]; op[1] = o.u[1]; op[2] = o.u[2];
}

// ---------------------------------------------------------------------------
// K0c: khT[b][d][j] = fp16(k[b][j][d])  (plain cast, no prescale) for PV GEMM
// ---------------------------------------------------------------------------
__global__ __launch_bounds__(256) void transpose_cast(const float* __restrict__ k,
                                                      f16* __restrict__ khT) {
  __shared__ f16 tile[64][65];
  int j0 = blockIdx.x * 64, d0 = blockIdx.y * 64;
  size_t bz = blockIdx.z;
  const float* kb = k + bz * (size_t)S_ * D_;
  f16* ob = khT + bz * (size_t)D_ * S_;
#pragma unroll
  for (int i = 0; i < 16; ++i) {
    int e = threadIdx.x + i * 256;
    int r = e >> 6, c = e & 63;              // r: j-local, c: d-local
    tile[c][r] = (f16)kb[(size_t)(j0 + r) * D_ + d0 + c];
  }
  __syncthreads();
#pragma unroll
  for (int i = 0; i < 16; ++i) {
    int e = threadIdx.x + i * 256;
    int r = e >> 6, c = e & 63;              // r: d-local, c: j-local
    ob[(size_t)(d0 + r) * S_ + j0 + c] = tile[r][c];
  }
}

// ---------------------------------------------------------------------------
// GEMM (B-transposed layout): C[m,n] = (sum_k A[m,k]*B[n,k]) * mult
// A: [S_][KA] fp16 row-major (batch stride S_*KA)
// B: [NN][KA] fp16 row-major (batch stride NN*KA)
// C: [S_][NN] fp32          (batch stride S_*NN)
// m97-style: 128x128 tile, 4 waves (2x2), 16x16x32 MFMA, dbuf LDS via
// global_load_lds width 16.
// ---------------------------------------------------------------------------
template <int KA, int NN>
__global__ __launch_bounds__(256) void gemm_bt(const f16* __restrict__ A,
                                               const f16* __restrict__ Bm,
                                               float* __restrict__ C,
                                               const float* scale_ptr, float factor) {
  __shared__ f16 As[2][128 * 32];
  __shared__ f16 Bs[2][128 * 32];
  const int tid = threadIdx.x;
  const int lane = tid & 63, wave = tid >> 6;
  const int wm = wave >> 1, wn = wave & 1;
  const size_t bz = blockIdx.z;
  const f16* Ab = A + bz * (size_t)S_ * KA + (size_t)blockIdx.x * 128 * KA;
  const f16* Bb = Bm + bz * (size_t)NN * KA + (size_t)blockIdx.y * 128 * KA;

  const int srow = wave * 32 + (lane >> 2);   // staging row (+p*16)
  const int scol = (lane & 3) * 8;            // staging col (elements)

  f32x4 acc[4][4];
#pragma unroll
  for (int i = 0; i < 4; ++i)
#pragma unroll
    for (int j = 0; j < 4; ++j)
#pragma unroll
      for (int r = 0; r < 4; ++r) acc[i][j][r] = 0.0f;

  auto stage = [&](int buf, int kt) {
#pragma unroll
    for (int p = 0; p < 2; ++p) {
      const f16* ga = Ab + (size_t)(srow + p * 16) * KA + kt * 32 + scol;
      const f16* gb = Bb + (size_t)(srow + p * 16) * KA + kt * 32 + scol;
      f16* la = &As[buf][(wave * 32 + p * 16) * 32];   // wave-uniform base
      f16* lb = &Bs[buf][(wave * 32 + p * 16) * 32];
      __builtin_amdgcn_global_load_lds((const __attribute__((address_space(1))) void*)ga,
                                       (__attribute__((address_space(3))) void*)la, 16, 0, 0);
      __builtin_amdgcn_global_load_lds((const __attribute__((address_space(1))) void*)gb,
                                       (__attribute__((address_space(3))) void*)lb, 16, 0, 0);
    }
  };

  constexpr int NT = KA / 32;
  stage(0, 0);
#pragma unroll 1
  for (int kt = 0; kt < NT; ++kt) {
    __syncthreads();                 // compiler drains vmcnt/lgkmcnt before barrier
    if (kt + 1 < NT) stage((kt + 1) & 1, kt + 1);
    const int cur = kt & 1;
    const int foff = (lane & 15) * 32 + (lane >> 4) * 8;
    f16x8 af[4], bf[4];
#pragma unroll
    for (int i = 0; i < 4; ++i)
      af[i] = *(const f16x8*)&As[cur][(wm * 64 + i * 16) * 32 + foff];
#pragma unroll
    for (int j = 0; j < 4; ++j)
      bf[j] = *(const f16x8*)&Bs[cur][(wn * 64 + j * 16) * 32 + foff];
#pragma unroll
    for (int i = 0; i < 4; ++i)
#pragma unroll
      for (int j = 0; j < 4; ++j)
        acc[i][j] = __builtin_amdgcn_mfma_f32_16x16x32_f16(af[i], bf[j], acc[i][j], 0, 0, 0);
  }

  float scl = factor;
  if (scale_ptr != nullptr) scl = factor * scale_ptr[0];
  float* Cb = C + bz * (size_t)S_ * NN;
  const int rowb = blockIdx.x * 128 + wm * 64 + ((lane >> 4) << 2);
  const int colb = blockIdx.y * 128 + wn * 64 + (lane & 15);
#pragma unroll
  for (int i = 0; i < 4; ++i)
#pragma unroll
    for (int j = 0; j < 4; ++j)
#pragma unroll
      for (int r = 0; r < 4; ++r)
        Cb[(size_t)(rowb + i * 16 + r) * NN + colb + j * 16] = acc[i][j][r] * scl;
}

// ---------------------------------------------------------------------------
// reductions
// ---------------------------------------------------------------------------
__device__ __forceinline__ float block_reduce_max(float v, float* red, int tid) {
#pragma unroll
  for (int o = 32; o > 0; o >>= 1) v = fmaxf(v, __shfl_xor(v, o, 64));
  __syncthreads();
  if ((tid & 63) == 0) red[tid >> 6] = v;
  __syncthreads();
  return fmaxf(fmaxf(red[0], red[1]), fmaxf(red[2], red[3]));
}
__device__ __forceinline__ float block_reduce_sum(float v, float* red, int tid) {
#pragma unroll
  for (int o = 32; o > 0; o >>= 1) v += __shfl_xor(v, o, 64);
  __syncthreads();
  if ((tid & 63) == 0) red[4 + (tid >> 6)] = v;
  __syncthreads();
  return (red[4] + red[5]) + (red[6] + red[7]);
}

// ---------------------------------------------------------------------------
// K2: row softmax for VALID query rows; padding rows -> P row = 0
// ---------------------------------------------------------------------------
__global__ __launch_bounds__(256) void softmax_rows(const float* __restrict__ scores,
                                                    const int* __restrict__ mask,
                                                    f16* __restrict__ P, int b0) {
  __shared__ float red[8];
  const int q = blockIdx.x, bl = blockIdx.y, bg = b0 + bl;
  const int tid = threadIdx.x;
  const float* srow = scores + ((size_t)bl * S_ + q) * S_;
  f16* prow = P + ((size_t)bl * S_ + q) * S_;
  if (mask[bg * S_ + q] == 0) {
    uint4 z = {0, 0, 0, 0};
    ((uint4*)prow)[tid] = z;   // 256 threads x 16B = 4096B row
    return;
  }
  float sv[8]; int fl[8];
  float lm = -3.4e38f;
#pragma unroll
  for (int i = 0; i < 8; ++i) {
    int j = i * 256 + tid;
    int ok = (j <= q) && (mask[bg * S_ + j] != 0);
    float s = srow[j];
    fl[i] = ok; sv[i] = s;
    if (ok) lm = fmaxf(lm, s);
  }
  float m = block_reduce_max(lm, red, tid);
  float ls = 0.0f;
#pragma unroll
  for (int i = 0; i < 8; ++i) {
    float e = fl[i] ? expf(sv[i] - m) : 0.0f;
    sv[i] = e; ls += e;
  }
  float sum = block_reduce_sum(ls, red, tid);
  float inv = 1.0f / sum;
#pragma unroll
  for (int i = 0; i < 8; ++i) prow[i * 256 + tid] = (f16)(sv[i] * inv);
}

// ---------------------------------------------------------------------------
// K4: padding query rows. Reference does fl(s - 1e9) uniformly -> scores
// quantize to a 64-wide fp32 grid; softmax = uniform average over the top
// bucket (lower buckets weigh exp(-64)~1.6e-28, negligible). Replicate that.
// Entries within 1e-3 of a rounding boundary near the top get an exact
// (double) recompute to match numpy's fp32 rounding decision.
// ---------------------------------------------------------------------------
__global__ __launch_bounds__(256) void padrows(const float* __restrict__ scores,
                                               const int* __restrict__ mask,
                                               const float* __restrict__ qg,
                                               const float* __restrict__ kg,
                                               const float* __restrict__ scale_ptr,
                                               float* __restrict__ out, int b0) {
  const int q = blockIdx.x, bl = blockIdx.y, bg = b0 + bl;
  if (mask[bg * S_ + q] != 0) return;
  const int tid = threadIdx.x;
  __shared__ float vrow[S_];
  __shared__ float red[8];
  const float* srow = scores + ((size_t)bl * S_ + q) * S_;
  const float scl = scale_ptr[0];

  float vv[8];
  float lm = -3.4e38f;
#pragma unroll
  for (int i = 0; i < 8; ++i) {
    int j = i * 256 + tid;
    float v = srow[j] - NEGC;         // fl(s - 1e9): quantized to 64-grid
    vrow[j] = v; vv[i] = v;
    lm = fmaxf(lm, v);
  }
  float g0 = block_reduce_max(lm, red, tid);

  float lm2 = -3.4e38f;
#pragma unroll 1
  for (int i = 0; i < 8; ++i) {
    int j = i * 256 + tid;
    float s = srow[j];
    float t = s * (1.0f / 64.0f);     // exact scaling by power of 2
    float rn = rintf(t);
    float dist = (0.5f - fabsf(t - rn)) * 64.0f;   // distance to rounding boundary
    float v = vv[i];
    if (dist < 1e-3f && v >= g0 - 64.5f) {
      const float* qr = qg + ((size_t)bg * S_ + q) * D_;
      const float* kr = kg + ((size_t)bg * S_ + j) * D_;
      double acc = 0.0;
      for (int t2 = 0; t2 < D_; ++t2) acc += (double)qr[t2] * (double)kr[t2];
      float sx = (float)acc * scl;
      v = sx - NEGC;
      vrow[j] = v;
    }
    lm2 = fmaxf(lm2, v);
  }
  float gf = block_reduce_max(lm2, red, tid);
  __syncthreads();

  // mean of k rows in the top bucket (deterministic j-order scan)
  float f0 = 0, f1 = 0, f2 = 0, f3 = 0; int cnt = 0;
  const float* kb = kg + (size_t)bg * S_ * D_;
#pragma unroll 1
  for (int j = 0; j < S_; ++j) {
    if (vrow[j] == gf) {
      const float4 kv = *(const float4*)(kb + (size_t)j * D_ + tid * 4);
      f0 += kv.x; f1 += kv.y; f2 += kv.z; f3 += kv.w; ++cnt;
    }
  }
  float invc = 1.0f / (float)cnt;
  float4 o = {f0 * invc, f1 * invc, f2 * invc, f3 * invc};
  *(float4*)(out + ((size_t)bg * S_ + q) * D_ + tid * 4) = o;
}

// ---------------------------------------------------------------------------
extern "C" void kernel_launch(void* const* d_in, const int* in_sizes, int n_in,
                              void* d_out, int out_size, void* d_ws, size_t ws_size,
                              hipStream_t stream) {
  (void)in_sizes; (void)n_in; (void)out_size;
  const float* q = (const float*)d_in[0];
  const float* k = (const float*)d_in[1];
  const int* mask = (const int*)d_in[2];
  const float* scale = (const float*)d_in[3];
  float* out = (float*)d_out;

  const size_t per_qx = (size_t)S_ * KEXP * 2;     // 12.58 MB
  const size_t per_khT = (size_t)D_ * S_ * 2;      //  4.19 MB
  const size_t per_sc = (size_t)S_ * S_ * 4;       // 16.78 MB
  const size_t per_P = (size_t)S_ * S_ * 2;        //  8.39 MB
  const size_t per_batch = 2 * per_qx + per_khT + per_sc + per_P;

  int nb = (int)(ws_size / per_batch);
  if (nb > B_) nb = B_;
  if (nb < 1) nb = 1;

  char* w = (char*)d_ws;
  f16* qx = (f16*)w;
  f16* kx = (f16*)(w + (size_t)nb * per_qx);
  f16* khT = (f16*)(w + (size_t)nb * per_qx * 2);
  float* sc = (float*)(w + (size_t)nb * (per_qx * 2 + per_khT));
  f16* P = (f16*)(w + (size_t)nb * (per_qx * 2 + per_khT + per_sc));

  for (int b0 = 0; b0 < B_; b0 += nb) {
    int cb = (B_ - b0 < nb) ? (B_ - b0) : nb;
    const float* qb = q + (size_t)b0 * S_ * D_;
    const float* kb = k + (size_t)b0 * S_ * D_;

    int blocks0 = cb * ((S_ * D_ / 8) / 256);  // cb * 1024
    split_expand<<<dim3(blocks0), dim3(256), 0, stream>>>(qb, qx, 0);
    split_expand<<<dim3(blocks0), dim3(256), 0, stream>>>(kb, kx, 1);
    transpose_cast<<<dim3(S_ / 64, D_ / 64, cb), dim3(256), 0, stream>>>(kb, khT);

    // scores = (q.k) * scale : factor 2^-12 undoes the 64x prescale on q,k
    gemm_bt<KEXP, S_><<<dim3(16, 16, cb), dim3(256), 0, stream>>>(
        qx, kx, sc, scale, 0.000244140625f);

    softmax_rows<<<dim3(S_, cb), dim3(256), 0, stream>>>(sc, mask, P, b0);

    gemm_bt<S_, D_><<<dim3(16, 8, cb), dim3(256), 0, stream>>>(
        P, khT, out + (size_t)b0 * S_ * D_, nullptr, 1.0f);

    padrows<<<dim3(S_, cb), dim3(256), 0, stream>>>(sc, mask, q, k, scale, out, b0);
  }
}

// Round 2
// 707.319 us; speedup vs baseline: 2.4065x; 2.4065x over previous
//
#include <hip/hip_runtime.h>
#include <hip/hip_bf16.h>
#include <stdint.h>

#define S_ 2048
#define D_ 1024
#define B_ 8
#define KEXP 3072            // 3 * D : [h,l,h] x [h,h,l] fp16 expansion
#define NEGC 1e9f

typedef _Float16 f16;
typedef _Float16 f16x8 __attribute__((ext_vector_type(8)));
typedef float f32x4 __attribute__((ext_vector_type(4)));

// ---------------------------------------------------------------------------
// K0a/K0b: split fp32 -> fp16 hi/lo 3-term expansion, input pre-scaled by 64.
// pattern A (q): out[3t]=h, out[3t+1]=l, out[3t+2]=h
// pattern B (k): out[3t]=h, out[3t+1]=h, out[3t+2]=l
// ---------------------------------------------------------------------------
__global__ __launch_bounds__(256) void split_expand(const float* __restrict__ in,
                                                    f16* __restrict__ out, int isB) {
  size_t idx = (size_t)blockIdx.x * 256 + threadIdx.x;   // one thread per 8 floats
  const float4* ip = (const float4*)(in + idx * 8);
  float4 a = ip[0], b = ip[1];
  float vv[8] = {a.x, a.y, a.z, a.w, b.x, b.y, b.z, b.w};
  union { f16 h[24]; uint4 u[3]; } o;
#pragma unroll
  for (int t = 0; t < 8; ++t) {
    float v = vv[t] * 64.0f;
    f16 h = (f16)v;
    float r = v - (float)h;      // exact (Sterbenz)
    f16 l = (f16)r;
    o.h[3 * t + 0] = h;
    o.h[3 * t + 1] = isB ? h : l;
    o.h[3 * t + 2] = isB ? l : h;
  }
  uint4* op = (uint4*)(out + idx * 24);
  op[0] = o.u[0]; op[1] = o.u[1]; op[2] = o.u[2];
}

// ---------------------------------------------------------------------------
// K0c: khT[b][d][j] = fp16(k[b][j][d])  (plain cast, no prescale) for PV GEMM
// ---------------------------------------------------------------------------
__global__ __launch_bounds__(256) void transpose_cast(const float* __restrict__ k,
                                                      f16* __restrict__ khT) {
  __shared__ f16 tile[64][65];
  int j0 = blockIdx.x * 64, d0 = blockIdx.y * 64;
  size_t bz = blockIdx.z;
  const float* kb = k + bz * (size_t)S_ * D_;
  f16* ob = khT + bz * (size_t)D_ * S_;
#pragma unroll
  for (int i = 0; i < 16; ++i) {
    int e = threadIdx.x + i * 256;
    int r = e >> 6, c = e & 63;              // r: j-local, c: d-local
    tile[c][r] = (f16)kb[(size_t)(j0 + r) * D_ + d0 + c];
  }
  __syncthreads();
#pragma unroll
  for (int i = 0; i < 16; ++i) {
    int e = threadIdx.x + i * 256;
    int r = e >> 6, c = e & 63;              // r: d-local, c: j-local
    ob[(size_t)(d0 + r) * S_ + j0 + c] = tile[r][c];
  }
}

// ---------------------------------------------------------------------------
// GEMM (B-transposed layout): C[m,n] = (sum_k A[m,k]*B[n,k]) * mult
// m97-style: 128x128 tile, 4 waves (2x2), 16x16x32 MFMA, dbuf LDS via
// global_load_lds width 16.
// ---------------------------------------------------------------------------
template <int KA, int NN>
__global__ __launch_bounds__(256) void gemm_bt(const f16* __restrict__ A,
                                               const f16* __restrict__ Bm,
                                               float* __restrict__ C,
                                               const float* scale_ptr, float factor) {
  __shared__ f16 As[2][128 * 32];
  __shared__ f16 Bs[2][128 * 32];
  const int tid = threadIdx.x;
  const int lane = tid & 63, wave = tid >> 6;
  const int wm = wave >> 1, wn = wave & 1;
  const size_t bz = blockIdx.z;
  const f16* Ab = A + bz * (size_t)S_ * KA + (size_t)blockIdx.x * 128 * KA;
  const f16* Bb = Bm + bz * (size_t)NN * KA + (size_t)blockIdx.y * 128 * KA;

  const int srow = wave * 32 + (lane >> 2);   // staging row (+p*16)
  const int scol = (lane & 3) * 8;            // staging col (elements)

  f32x4 acc[4][4];
#pragma unroll
  for (int i = 0; i < 4; ++i)
#pragma unroll
    for (int j = 0; j < 4; ++j)
#pragma unroll
      for (int r = 0; r < 4; ++r) acc[i][j][r] = 0.0f;

  auto stage = [&](int buf, int kt) {
#pragma unroll
    for (int p = 0; p < 2; ++p) {
      const f16* ga = Ab + (size_t)(srow + p * 16) * KA + kt * 32 + scol;
      const f16* gb = Bb + (size_t)(srow + p * 16) * KA + kt * 32 + scol;
      f16* la = &As[buf][(wave * 32 + p * 16) * 32];   // wave-uniform base
      f16* lb = &Bs[buf][(wave * 32 + p * 16) * 32];
      __builtin_amdgcn_global_load_lds((const __attribute__((address_space(1))) void*)ga,
                                       (__attribute__((address_space(3))) void*)la, 16, 0, 0);
      __builtin_amdgcn_global_load_lds((const __attribute__((address_space(1))) void*)gb,
                                       (__attribute__((address_space(3))) void*)lb, 16, 0, 0);
    }
  };

  constexpr int NT = KA / 32;
  stage(0, 0);
#pragma unroll 1
  for (int kt = 0; kt < NT; ++kt) {
    __syncthreads();                 // compiler drains vmcnt/lgkmcnt before barrier
    if (kt + 1 < NT) stage((kt + 1) & 1, kt + 1);
    const int cur = kt & 1;
    const int foff = (lane & 15) * 32 + (lane >> 4) * 8;
    f16x8 af[4], bf[4];
#pragma unroll
    for (int i = 0; i < 4; ++i)
      af[i] = *(const f16x8*)&As[cur][(wm * 64 + i * 16) * 32 + foff];
#pragma unroll
    for (int j = 0; j < 4; ++j)
      bf[j] = *(const f16x8*)&Bs[cur][(wn * 64 + j * 16) * 32 + foff];
#pragma unroll
    for (int i = 0; i < 4; ++i)
#pragma unroll
      for (int j = 0; j < 4; ++j)
        acc[i][j] = __builtin_amdgcn_mfma_f32_16x16x32_f16(af[i], bf[j], acc[i][j], 0, 0, 0);
  }

  float scl = factor;
  if (scale_ptr != nullptr) scl = factor * scale_ptr[0];
  float* Cb = C + bz * (size_t)S_ * NN;
  const int rowb = blockIdx.x * 128 + wm * 64 + ((lane >> 4) << 2);
  const int colb = blockIdx.y * 128 + wn * 64 + (lane & 15);
#pragma unroll
  for (int i = 0; i < 4; ++i)
#pragma unroll
    for (int j = 0; j < 4; ++j)
#pragma unroll
      for (int r = 0; r < 4; ++r)
        Cb[(size_t)(rowb + i * 16 + r) * NN + colb + j * 16] = acc[i][j][r] * scl;
}

// ---------------------------------------------------------------------------
// reductions
// ---------------------------------------------------------------------------
__device__ __forceinline__ float block_reduce_max(float v, float* red, int tid) {
#pragma unroll
  for (int o = 32; o > 0; o >>= 1) v = fmaxf(v, __shfl_xor(v, o, 64));
  __syncthreads();
  if ((tid & 63) == 0) red[tid >> 6] = v;
  __syncthreads();
  return fmaxf(fmaxf(red[0], red[1]), fmaxf(red[2], red[3]));
}
__device__ __forceinline__ float block_reduce_sum(float v, float* red, int tid) {
#pragma unroll
  for (int o = 32; o > 0; o >>= 1) v += __shfl_xor(v, o, 64);
  __syncthreads();
  if ((tid & 63) == 0) red[4 + (tid >> 6)] = v;
  __syncthreads();
  return (red[4] + red[5]) + (red[6] + red[7]);
}

// ---------------------------------------------------------------------------
// K2: row softmax for VALID query rows; padding rows -> P row = 0.
// Thread owns 8 contiguous columns: float4 loads, 16B f16 stores.
// ---------------------------------------------------------------------------
__global__ __launch_bounds__(256) void softmax_rows(const float* __restrict__ scores,
                                                    const int* __restrict__ mask,
                                                    f16* __restrict__ P, int b0) {
  __shared__ float red[8];
  const int q = blockIdx.x, bl = blockIdx.y, bg = b0 + bl;
  const int tid = threadIdx.x;
  const float* srow = scores + ((size_t)bl * S_ + q) * S_;
  f16* prow = P + ((size_t)bl * S_ + q) * S_;
  if (mask[bg * S_ + q] == 0) {
    uint4 z = {0, 0, 0, 0};
    ((uint4*)prow)[tid] = z;   // 256 threads x 16B = 4096B row
    return;
  }
  const int j0 = tid * 8;
  float4 s0v = *(const float4*)(srow + j0);
  float4 s1v = *(const float4*)(srow + j0 + 4);
  int4 m0 = *(const int4*)(mask + (size_t)bg * S_ + j0);
  int4 m1 = *(const int4*)(mask + (size_t)bg * S_ + j0 + 4);
  float sv[8] = {s0v.x, s0v.y, s0v.z, s0v.w, s1v.x, s1v.y, s1v.z, s1v.w};
  int mk[8] = {m0.x, m0.y, m0.z, m0.w, m1.x, m1.y, m1.z, m1.w};
  int fl[8];
  float lm = -3.4e38f;
#pragma unroll
  for (int i = 0; i < 8; ++i) {
    fl[i] = (j0 + i <= q) && (mk[i] != 0);
    if (fl[i]) lm = fmaxf(lm, sv[i]);
  }
  float m = block_reduce_max(lm, red, tid);
  float ls = 0.0f;
#pragma unroll
  for (int i = 0; i < 8; ++i) {
    float e = fl[i] ? expf(sv[i] - m) : 0.0f;
    sv[i] = e; ls += e;
  }
  float sum = block_reduce_sum(ls, red, tid);
  float inv = 1.0f / sum;
  union { f16 h[8]; uint4 u; } ow;
#pragma unroll
  for (int i = 0; i < 8; ++i) ow.h[i] = (f16)(sv[i] * inv);
  *(uint4*)(prow + j0) = ow.u;
}

// ---------------------------------------------------------------------------
// K4: padding query rows. Reference does fl(s - 1e9) uniformly -> scores
// quantize to a 64-wide fp32 grid (boundaries at odd multiples of 32);
// softmax = uniform average over the top bucket. Entries within 1e-3 of a
// boundary near the top get an exact (double) recompute to match numpy's
// fp32 rounding decision.
// Parallel version: thread owns 8 contiguous j; ordered match list built via
// block prefix scan (deterministic, j-sorted); cooperative accumulation.
// ---------------------------------------------------------------------------
__global__ __launch_bounds__(256) void padrows(const float* __restrict__ scores,
                                               const int* __restrict__ mask,
                                               const float* __restrict__ qg,
                                               const float* __restrict__ kg,
                                               const float* __restrict__ scale_ptr,
                                               float* __restrict__ out, int b0) {
  const int q = blockIdx.x, bl = blockIdx.y, bg = b0 + bl;
  if (mask[bg * S_ + q] != 0) return;
  const int tid = threadIdx.x;
  __shared__ int idxs[S_];
  __shared__ int scn[256];
  __shared__ float red[8];
  const float* srow = scores + ((size_t)bl * S_ + q) * S_;
  const float scl = scale_ptr[0];
  const int j0 = tid * 8;

  float4 s0v = *(const float4*)(srow + j0);
  float4 s1v = *(const float4*)(srow + j0 + 4);
  float sv[8] = {s0v.x, s0v.y, s0v.z, s0v.w, s1v.x, s1v.y, s1v.z, s1v.w};
  float vv[8];
  float lm = -3.4e38f;
#pragma unroll
  for (int i = 0; i < 8; ++i) {
    vv[i] = sv[i] - NEGC;             // fl(s - 1e9): quantized to 64-grid
    lm = fmaxf(lm, vv[i]);
  }
  float g0 = block_reduce_max(lm, red, tid);

  float lm2 = -3.4e38f;
#pragma unroll 1
  for (int i = 0; i < 8; ++i) {
    float s = sv[i];
    float t = s * (1.0f / 64.0f);     // exact scaling by power of 2
    float rn = rintf(t);
    float dist = (0.5f - fabsf(t - rn)) * 64.0f;   // distance to rounding boundary
    float v = vv[i];
    if (dist < 1e-3f && v >= g0 - 64.5f) {
      const float* qr = qg + ((size_t)bg * S_ + q) * D_;
      const float* kr = kg + ((size_t)bg * S_ + j0 + i) * D_;
      double acc = 0.0;
      for (int t2 = 0; t2 < D_; ++t2) acc += (double)qr[t2] * (double)kr[t2];
      float sx = (float)acc * scl;
      v = sx - NEGC;
    }
    vv[i] = v;
    lm2 = fmaxf(lm2, v);
  }
  float gf = block_reduce_max(lm2, red, tid);

  // ordered (j-sorted) match collection via block prefix scan
  int local = 0, flags = 0;
#pragma unroll
  for (int i = 0; i < 8; ++i) {
    int mt = (vv[i] == gf) ? 1 : 0;
    flags |= mt << i;
    local += mt;
  }
  scn[tid] = local;
  __syncthreads();
#pragma unroll
  for (int o = 1; o < 256; o <<= 1) {
    int v2 = (tid >= o) ? scn[tid - o] : 0;
    __syncthreads();
    scn[tid] += v2;
    __syncthreads();
  }
  int total = scn[255];
  int base = scn[tid] - local;
  int w = 0;
#pragma unroll
  for (int i = 0; i < 8; ++i)
    if ((flags >> i) & 1) idxs[base + (w++)] = j0 + i;
  __syncthreads();

  // cooperative mean over matched k rows (thread owns 4 d-columns)
  const float* kb = kg + (size_t)bg * S_ * D_;
  float a0 = 0, a1 = 0, a2 = 0, a3 = 0;
#pragma unroll 4
  for (int m2 = 0; m2 < total; ++m2) {
    const float4 kv = *(const float4*)(kb + (size_t)idxs[m2] * D_ + tid * 4);
    a0 += kv.x; a1 += kv.y; a2 += kv.z; a3 += kv.w;
  }
  float invc = 1.0f / (float)total;
  float4 o = {a0 * invc, a1 * invc, a2 * invc, a3 * invc};
  *(float4*)(out + ((size_t)bg * S_ + q) * D_ + tid * 4) = o;
}

// ---------------------------------------------------------------------------
extern "C" void kernel_launch(void* const* d_in, const int* in_sizes, int n_in,
                              void* d_out, int out_size, void* d_ws, size_t ws_size,
                              hipStream_t stream) {
  (void)in_sizes; (void)n_in; (void)out_size;
  const float* q = (const float*)d_in[0];
  const float* k = (const float*)d_in[1];
  const int* mask = (const int*)d_in[2];
  const float* scale = (const float*)d_in[3];
  float* out = (float*)d_out;

  const size_t per_qx = (size_t)S_ * KEXP * 2;     // 12.58 MB
  const size_t per_khT = (size_t)D_ * S_ * 2;      //  4.19 MB
  const size_t per_sc = (size_t)S_ * S_ * 4;       // 16.78 MB
  const size_t per_P = (size_t)S_ * S_ * 2;        //  8.39 MB
  const size_t per_batch = 2 * per_qx + per_khT + per_sc + per_P;

  int nb = (int)(ws_size / per_batch);
  if (nb > B_) nb = B_;
  if (nb < 1) nb = 1;

  char* w = (char*)d_ws;
  f16* qx = (f16*)w;
  f16* kx = (f16*)(w + (size_t)nb * per_qx);
  f16* khT = (f16*)(w + (size_t)nb * per_qx * 2);
  float* sc = (float*)(w + (size_t)nb * (per_qx * 2 + per_khT));
  f16* P = (f16*)(w + (size_t)nb * (per_qx * 2 + per_khT + per_sc));

  for (int b0 = 0; b0 < B_; b0 += nb) {
    int cb = (B_ - b0 < nb) ? (B_ - b0) : nb;
    const float* qb = q + (size_t)b0 * S_ * D_;
    const float* kb = k + (size_t)b0 * S_ * D_;

    int blocks0 = cb * ((S_ * D_ / 8) / 256);  // cb * 1024
    split_expand<<<dim3(blocks0), dim3(256), 0, stream>>>(qb, qx, 0);
    split_expand<<<dim3(blocks0), dim3(256), 0, stream>>>(kb, kx, 1);
    transpose_cast<<<dim3(S_ / 64, D_ / 64, cb), dim3(256), 0, stream>>>(kb, khT);

    // scores = (q.k) * scale : factor 2^-12 undoes the 64x prescale on q,k
    gemm_bt<KEXP, S_><<<dim3(16, 16, cb), dim3(256), 0, stream>>>(
        qx, kx, sc, scale, 0.000244140625f);

    softmax_rows<<<dim3(S_, cb), dim3(256), 0, stream>>>(sc, mask, P, b0);

    gemm_bt<S_, D_><<<dim3(16, 8, cb), dim3(256), 0, stream>>>(
        P, khT, out + (size_t)b0 * S_ * D_, nullptr, 1.0f);

    padrows<<<dim3(S_, cb), dim3(256), 0, stream>>>(sc, mask, q, k, scale, out, b0);
  }
}